// Round 1
// baseline (1674.595 us; speedup 1.0000x reference)
//
#include <hip/hip_runtime.h>
#include <math.h>

#define EPSF 1e-5f

// ---------------- instance-norm stats over time axis ----------------
// x: [B=256, L=512, C=32]; one block per b; outputs mean/std/rstd [B,32]
__global__ __launch_bounds__(256) void stats_kernel(
    const float* __restrict__ x, float* __restrict__ meanp,
    float* __restrict__ stdp, float* __restrict__ rstdp)
{
  int b = blockIdx.x;
  int tid = threadIdx.x;
  int c = tid & 31, ls = tid >> 5;           // 8 l-slices x 32 channels
  const float* xb = x + (size_t)b * 16384;
  float s = 0.f, s2 = 0.f;
  for (int l = ls; l < 512; l += 8) {
    float v = xb[l * 32 + c];
    s += v; s2 += v * v;
  }
  __shared__ float sb[8][32];
  __shared__ float sb2[8][32];
  sb[ls][c] = s; sb2[ls][c] = s2;
  __syncthreads();
  if (ls == 0) {
#pragma unroll
    for (int i = 1; i < 8; ++i) { s += sb[i][c]; s2 += sb2[i][c]; }
    float m = s * (1.f / 512.f);
    float var = s2 * (1.f / 512.f) - m * m;
    float sd = sqrtf(var + EPSF);
    meanp[b * 32 + c] = m;
    stdp[b * 32 + c] = sd;
    rstdp[b * 32 + c] = 1.f / sd;
  }
}

// ---------------- Fourier-mask -> time-domain circular conv kernel ----------------
// k_nb[t] = (1/512)(m0 + (-1)^t m256 + 2 sum_{f=1..255} m_f cos(2pi f t/512))
// Stored duplicated: kf[nb*1024 + t] = kf[nb*1024 + t + 512] = k_nb[t]
__global__ __launch_bounds__(256) void kfilt_kernel(
    const float* __restrict__ mw, float* __restrict__ kf)
{
  int gid = blockIdx.x * 256 + threadIdx.x;  // NB*512 = 2048 threads
  int nb = gid >> 9, t = gid & 511;
  const float* m = mw + nb * 257;
  float s0 = 1.f / (1.f + expf(-m[0]));
  float sN = 1.f / (1.f + expf(-m[256]));
  float acc = s0 + ((t & 1) ? -sN : sN);
  for (int f = 1; f < 256; ++f) {
    float sig = 1.f / (1.f + expf(-m[f]));
    int tf = (t * f) & 511;                  // exact phase mod 512
    acc += 2.f * sig * cosf(6.28318530717958647f * (float)tf * (1.f / 512.f));
  }
  float kv = acc * (1.f / 512.f);
  kf[nb * 1024 + t] = kv;
  kf[nb * 1024 + t + 512] = kv;
}

// ---------------- circular conv: xi[nb,b,l,c] = sum_l' k[(l-l')&511]*xn[b,l',c] ----------------
// grid (b=256, nb=4, ch=2); each block handles 16 of 32 channels; normalizes x on load.
__global__ __launch_bounds__(256) void conv_kernel(
    const float* __restrict__ x, const float* __restrict__ meanp,
    const float* __restrict__ rstdp, const float* __restrict__ kf,
    float* __restrict__ xi)
{
  __shared__ float xs[512 * 16];   // 32 KB: xn for 16 channels
  __shared__ float ks[1024];       // 4 KB: duplicated filter
  int b = blockIdx.x, nb = blockIdx.y, ch = blockIdx.z;
  int tid = threadIdx.x;
  int cq = tid & 3;                // which float4 of the 16-channel slab
  const float* xb = x + (size_t)b * 16384 + ch * 16;
  float4 m4 = *(const float4*)(meanp + b * 32 + ch * 16 + cq * 4);
  float4 r4 = *(const float4*)(rstdp + b * 32 + ch * 16 + cq * 4);
#pragma unroll
  for (int i = 0; i < 8; ++i) {
    int l = (tid + i * 256) >> 2;
    float4 v = *(const float4*)(xb + l * 32 + cq * 4);
    v.x = (v.x - m4.x) * r4.x;
    v.y = (v.y - m4.y) * r4.y;
    v.z = (v.z - m4.z) * r4.z;
    v.w = (v.w - m4.w) * r4.w;
    *(float4*)&xs[l * 16 + cq * 4] = v;
  }
  *(float4*)&ks[tid * 4] = *(const float4*)(kf + nb * 1024 + tid * 4);
  __syncthreads();

  int c0 = cq * 4;
  int lg = tid >> 2;
  int l0 = lg * 8;                 // 8 output rows per thread, 4 channels
  float acc[8][4] = {};
  for (int lp = 0; lp < 512; lp += 4) {
    float4 xv[4];
#pragma unroll
    for (int u = 0; u < 4; ++u)
      xv[u] = *(const float4*)&xs[(lp + u) * 16 + c0];
    float kw[12];
    const float* kbp = &ks[l0 - lp + 508];   // 16B-aligned: l0%8==0, lp%4==0
#pragma unroll
    for (int j = 0; j < 3; ++j)
      *(float4*)&kw[4 * j] = *(const float4*)(kbp + 4 * j);
#pragma unroll
    for (int u = 0; u < 4; ++u) {
      const float* xvp = (const float*)&xv[u];
#pragma unroll
      for (int li = 0; li < 8; ++li) {
        float kv = kw[li - u + 4];           // = k[(l0+li-(lp+u)) & 511]
        acc[li][0] = fmaf(kv, xvp[0], acc[li][0]);
        acc[li][1] = fmaf(kv, xvp[1], acc[li][1]);
        acc[li][2] = fmaf(kv, xvp[2], acc[li][2]);
        acc[li][3] = fmaf(kv, xvp[3], acc[li][3]);
      }
    }
  }
  float* o = xi + ((size_t)nb * 256 + b) * 16384 + ch * 16;
#pragma unroll
  for (int li = 0; li < 8; ++li)
    *(float4*)(o + (l0 + li) * 32 + c0) =
        make_float4(acc[li][0], acc[li][1], acc[li][2], acc[li][3]);
}

// ---------------- generic batched NT GEMM: C = A[M,K] @ B[N,K]^T (+bias)(+Add)(relu) ----------------
// 64x64 tile, 256 threads, 4x4 per thread. blockIdx.z = nb batch.
__global__ __launch_bounds__(256) void gemm_nt(
    const float* __restrict__ A, int lda, long long batchA,
    const float* __restrict__ B, long long batchB,
    const float* __restrict__ bias, long long batchBias,
    const float* __restrict__ Add, int ldadd, long long batchAdd,
    float* __restrict__ C, int ldc, long long batchC,
    int M, int N, int K, int relu)
{
  int bz = blockIdx.z;
  A += (long long)bz * batchA;
  B += (long long)bz * batchB;
  C += (long long)bz * batchC;

  __shared__ float As[16][68];   // [k][m], +4 pad keeps 16B alignment, breaks conflicts
  __shared__ float Bs[16][68];

  int tid = threadIdx.x;
  int lr = tid >> 2;            // 0..63 tile row for loading
  int lk = (tid & 3) << 2;      // 0,4,8,12 k-offset
  int tm = ((tid >> 4) & 15) << 2;
  int tn = (tid & 15) << 2;
  int bm = blockIdx.y << 6;
  int bn = blockIdx.x << 6;

  const float* Ap = A + (long long)(bm + lr) * lda + lk;
  const float* Bp = B + (long long)(bn + lr) * K + lk;

  float acc[4][4] = {};

  for (int kb = 0; kb < K; kb += 16) {
    float4 av = *(const float4*)(Ap + kb);
    float4 bv = *(const float4*)(Bp + kb);
    As[lk + 0][lr] = av.x; As[lk + 1][lr] = av.y;
    As[lk + 2][lr] = av.z; As[lk + 3][lr] = av.w;
    Bs[lk + 0][lr] = bv.x; Bs[lk + 1][lr] = bv.y;
    Bs[lk + 2][lr] = bv.z; Bs[lk + 3][lr] = bv.w;
    __syncthreads();
#pragma unroll
    for (int k = 0; k < 16; ++k) {
      float4 a4 = *(const float4*)&As[k][tm];
      float4 b4 = *(const float4*)&Bs[k][tn];
      const float* a = (const float*)&a4;
      const float* bq = (const float*)&b4;
#pragma unroll
      for (int i = 0; i < 4; ++i)
#pragma unroll
        for (int j = 0; j < 4; ++j)
          acc[i][j] = fmaf(a[i], bq[j], acc[i][j]);
    }
    __syncthreads();
  }

  float4 bb4 = make_float4(0.f, 0.f, 0.f, 0.f);
  if (bias) bb4 = *(const float4*)(bias + (long long)bz * batchBias + bn + tn);
  const float* addp = Add ? Add + (long long)bz * batchAdd : nullptr;
#pragma unroll
  for (int i = 0; i < 4; ++i) {
    int m = bm + tm + i;
    float4 o = make_float4(acc[i][0] + bb4.x, acc[i][1] + bb4.y,
                           acc[i][2] + bb4.z, acc[i][3] + bb4.w);
    if (addp) {
      float4 ad = *(const float4*)(addp + (long long)m * ldadd + bn + tn);
      o.x += ad.x; o.y += ad.y; o.z += ad.z; o.w += ad.w;
    }
    if (relu) {
      o.x = fmaxf(o.x, 0.f); o.y = fmaxf(o.y, 0.f);
      o.z = fmaxf(o.z, 0.f); o.w = fmaxf(o.w, 0.f);
    }
    *(float4*)(C + (long long)m * ldc + bn + tn) = o;
  }
}

// ---------------- LayerNorm over last dim (512) of preds [NB,B,4,512], in place ----------------
__global__ __launch_bounds__(256) void ln_kernel(
    float* __restrict__ p, const float* __restrict__ g, const float* __restrict__ bb)
{
  int row = blockIdx.x;           // NB*B*4 = 4096 rows
  int nb = row >> 10;
  float* pr = p + (size_t)row * 512;
  int tid = threadIdx.x;
  float v0 = pr[tid], v1 = pr[tid + 256];
  float s = v0 + v1, s2 = v0 * v0 + v1 * v1;
#pragma unroll
  for (int o = 32; o > 0; o >>= 1) {
    s += __shfl_down(s, o);
    s2 += __shfl_down(s2, o);
  }
  __shared__ float rs[4];
  __shared__ float rs2[4];
  int w = tid >> 6;
  if ((tid & 63) == 0) { rs[w] = s; rs2[w] = s2; }
  __syncthreads();
  s = rs[0] + rs[1] + rs[2] + rs[3];
  s2 = rs2[0] + rs2[1] + rs2[2] + rs2[3];
  float mval = s * (1.f / 512.f);
  float var = s2 * (1.f / 512.f) - mval * mval;
  float r = 1.f / sqrtf(var + EPSF);
  const float* gn = g + nb * 512;
  const float* bn = bb + nb * 512;
  pr[tid] = (v0 - mval) * r * gn[tid] + bn[tid];
  pr[tid + 256] = (v1 - mval) * r * gn[tid + 256] + bn[tid + 256];
}

// ---------------- final: out = (sum_nb deco) * std + mean ----------------
__global__ __launch_bounds__(256) void final_kernel(
    const float* __restrict__ deco, const float* __restrict__ meanp,
    const float* __restrict__ stdp, float* __restrict__ out)
{
  int t = blockIdx.x * 256 + threadIdx.x;   // float4 index over [B,4,64,8]
  int b = t >> 11;
  int r = t & 2047;
  int s = r >> 9;
  int p = (r >> 3) & 63;
  int cq = r & 7;
  size_t base = ((size_t)(b * 4 + s)) * 2048 + p * 32 + cq * 4;
  const size_t nbs = 1024ull * 2048ull;
  float4 a0 = *(const float4*)(deco + base);
  float4 a1 = *(const float4*)(deco + nbs + base);
  float4 a2 = *(const float4*)(deco + 2 * nbs + base);
  float4 a3 = *(const float4*)(deco + 3 * nbs + base);
  float4 m4 = *(const float4*)(meanp + b * 32 + cq * 4);
  float4 s4 = *(const float4*)(stdp + b * 32 + cq * 4);
  float4 o;
  o.x = (a0.x + a1.x + a2.x + a3.x) * s4.x + m4.x;
  o.y = (a0.y + a1.y + a2.y + a3.y) * s4.y + m4.y;
  o.z = (a0.z + a1.z + a2.z + a3.z) * s4.z + m4.z;
  o.w = (a0.w + a1.w + a2.w + a3.w) * s4.w + m4.w;
  *(float4*)(out + (size_t)t * 4) = o;
}

extern "C" void kernel_launch(void* const* d_in, const int* in_sizes, int n_in,
                              void* d_out, int out_size, void* d_ws, size_t ws_size,
                              hipStream_t stream) {
  const float* x_enc  = (const float*)d_in[0];
  const float* mask_w = (const float*)d_in[4];
  const float* enc_w1 = (const float*)d_in[5];
  const float* enc_b1 = (const float*)d_in[6];
  const float* enc_w2 = (const float*)d_in[7];
  const float* enc_b2 = (const float*)d_in[8];
  const float* wxh    = (const float*)d_in[9];
  const float* whh    = (const float*)d_in[10];
  const float* ln_g   = (const float*)d_in[11];
  const float* ln_b   = (const float*)d_in[12];
  const float* dec_w1 = (const float*)d_in[13];
  const float* dec_b1 = (const float*)d_in[14];
  const float* dec_w2 = (const float*)d_in[15];
  const float* dec_b2 = (const float*)d_in[16];
  float* out = (float*)d_out;
  float* ws  = (float*)d_ws;

  // workspace layout (floats); total 32,534,528 floats = ~124 MiB
  float* MEAN  = ws;                    // 8192
  float* STD   = ws + 8192;             // 8192
  float* RSTD  = ws + 16384;            // 8192
  float* KF    = ws + 24576;            // 4096
  float* XI    = ws + 28672;            // 16,777,216  [NB,B,512,32]
  float* DBUF  = XI;                    // 4,194,304  (reuses XI after enc1)
  float* DECO  = XI + 4194304;          // 8,388,608  (reuses XI after enc1)
  float* ENCB  = XI + 16777216;         // 8,388,608  [NB,2048,1024]
  float* XP    = ENCB;                  // 4,194,304  (reuses ENCB after enc2)
  float* ENC2  = ENCB + 8388608;        // 4,194,304  [NB,2048,512]
  float* H0    = ENC2 + 4194304;        // 524,288
  float* H1    = H0 + 524288;           // 524,288
  float* PREDS = H1 + 524288;           // 2,097,152  [NB,B,4,512]

  stats_kernel<<<256, 256, 0, stream>>>(x_enc, MEAN, STD, RSTD);
  kfilt_kernel<<<8, 256, 0, stream>>>(mask_w, KF);
  conv_kernel<<<dim3(256, 4, 2), 256, 0, stream>>>(x_enc, MEAN, RSTD, KF, XI);

  // enc1: [2048,2048]@[1024,2048]^T + b, relu     per nb
  gemm_nt<<<dim3(16, 32, 4), 256, 0, stream>>>(
      XI, 2048, 4194304LL, enc_w1, 2097152LL, enc_b1, 1024LL,
      nullptr, 0, 0LL, ENCB, 1024, 2097152LL, 2048, 1024, 2048, 1);
  // enc2: [2048,1024]@[512,1024]^T + b
  gemm_nt<<<dim3(8, 32, 4), 256, 0, stream>>>(
      ENCB, 1024, 2097152LL, enc_w2, 524288LL, enc_b2, 512LL,
      nullptr, 0, 0LL, ENC2, 512, 1048576LL, 2048, 512, 1024, 0);
  // xp = enc2 @ wxh^T  (RNN input projection for all 8 timesteps at once)
  gemm_nt<<<dim3(8, 32, 4), 256, 0, stream>>>(
      ENC2, 512, 1048576LL, wxh, 262144LL, nullptr, 0LL,
      nullptr, 0, 0LL, XP, 512, 1048576LL, 2048, 512, 512, 0);

  // recurrence: h_0 = xp_0;  h_f = h_{f-1} @ whh^T + xp_f  (f=1..7)
  const float* hin = XP; int lda_h = 4096; long long batchA_h = 1048576LL;
  float* hbuf[2] = {H0, H1};
  for (int f = 1; f < 8; ++f) {
    float* hout = hbuf[(f - 1) & 1];
    gemm_nt<<<dim3(8, 4, 4), 256, 0, stream>>>(
        hin, lda_h, batchA_h, whh, 262144LL, nullptr, 0LL,
        XP + f * 512, 4096, 1048576LL, hout, 512, 131072LL, 256, 512, 512, 0);
    hin = hout; lda_h = 512; batchA_h = 131072LL;
  }
  // free-run: preds_s = h @ whh^T, h <- preds_s  (s=0..3)
  for (int s = 0; s < 4; ++s) {
    gemm_nt<<<dim3(8, 4, 4), 256, 0, stream>>>(
        hin, lda_h, batchA_h, whh, 262144LL, nullptr, 0LL,
        nullptr, 0, 0LL, PREDS + s * 512, 2048, 524288LL, 256, 512, 512, 0);
    hin = PREDS + s * 512; lda_h = 2048; batchA_h = 524288LL;
  }

  ln_kernel<<<4096, 256, 0, stream>>>(PREDS, ln_g, ln_b);

  // dec1: [1024,512]@[1024,512]^T + b, relu
  gemm_nt<<<dim3(16, 16, 4), 256, 0, stream>>>(
      PREDS, 512, 524288LL, dec_w1, 524288LL, dec_b1, 1024LL,
      nullptr, 0, 0LL, DBUF, 1024, 1048576LL, 1024, 1024, 512, 1);
  // dec2: [1024,1024]@[2048,1024]^T + b
  gemm_nt<<<dim3(32, 16, 4), 256, 0, stream>>>(
      DBUF, 1024, 1048576LL, dec_w2, 2097152LL, dec_b2, 2048LL,
      nullptr, 0, 0LL, DECO, 2048, 2097152LL, 1024, 2048, 1024, 0);

  final_kernel<<<2048, 256, 0, stream>>>(DECO, MEAN, STD, out);
}

// Round 2
// 1089.173 us; speedup vs baseline: 1.5375x; 1.5375x over previous
//
#include <hip/hip_runtime.h>
#include <hip/hip_bf16.h>
#include <math.h>

#define EPSF 1e-5f

typedef __attribute__((ext_vector_type(8))) short bf16x8;
typedef __attribute__((ext_vector_type(4))) float f32x4;

__device__ __forceinline__ void gld16(const void* g, void* l) {
  __builtin_amdgcn_global_load_lds(
      (const __attribute__((address_space(1))) unsigned int*)g,
      (__attribute__((address_space(3))) unsigned int*)l, 16, 0, 0);
}

// ---------------- instance-norm stats over time axis ----------------
__global__ __launch_bounds__(256) void stats_kernel(
    const float* __restrict__ x, float* __restrict__ meanp,
    float* __restrict__ stdp, float* __restrict__ rstdp)
{
  int b = blockIdx.x;
  int tid = threadIdx.x;
  int c = tid & 31, ls = tid >> 5;
  const float* xb = x + (size_t)b * 16384;
  float s = 0.f, s2 = 0.f;
  for (int l = ls; l < 512; l += 8) {
    float v = xb[l * 32 + c];
    s += v; s2 += v * v;
  }
  __shared__ float sb[8][32];
  __shared__ float sb2[8][32];
  sb[ls][c] = s; sb2[ls][c] = s2;
  __syncthreads();
  if (ls == 0) {
#pragma unroll
    for (int i = 1; i < 8; ++i) { s += sb[i][c]; s2 += sb2[i][c]; }
    float m = s * (1.f / 512.f);
    float var = s2 * (1.f / 512.f) - m * m;
    float sd = sqrtf(var + EPSF);
    meanp[b * 32 + c] = m;
    stdp[b * 32 + c] = sd;
    rstdp[b * 32 + c] = 1.f / sd;
  }
}

// ---------------- Fourier-mask -> time-domain circular conv kernel ----------------
__global__ __launch_bounds__(256) void kfilt_kernel(
    const float* __restrict__ mw, float* __restrict__ kf)
{
  int gid = blockIdx.x * 256 + threadIdx.x;
  int nb = gid >> 9, t = gid & 511;
  const float* m = mw + nb * 257;
  float s0 = 1.f / (1.f + expf(-m[0]));
  float sN = 1.f / (1.f + expf(-m[256]));
  float acc = s0 + ((t & 1) ? -sN : sN);
  for (int f = 1; f < 256; ++f) {
    float sig = 1.f / (1.f + expf(-m[f]));
    int tf = (t * f) & 511;
    acc += 2.f * sig * cosf(6.28318530717958647f * (float)tf * (1.f / 512.f));
  }
  float kv = acc * (1.f / 512.f);
  kf[nb * 1024 + t] = kv;
  kf[nb * 1024 + t + 512] = kv;
}

// ---------------- circular conv; writes bf16-hi output in enc1-A layout ----------------
// XIH per nb: [2048 rows = b*8+f][2048 cols = p*32+c] bf16
__global__ __launch_bounds__(256) void conv_kernel(
    const float* __restrict__ x, const float* __restrict__ meanp,
    const float* __restrict__ rstdp, const float* __restrict__ kf,
    __hip_bfloat16* __restrict__ xih)
{
  __shared__ float xs[512 * 16];
  __shared__ float ks[1024];
  int b = blockIdx.x, nb = blockIdx.y, ch = blockIdx.z;
  int tid = threadIdx.x;
  int cq = tid & 3;
  const float* xb = x + (size_t)b * 16384 + ch * 16;
  float4 m4 = *(const float4*)(meanp + b * 32 + ch * 16 + cq * 4);
  float4 r4 = *(const float4*)(rstdp + b * 32 + ch * 16 + cq * 4);
#pragma unroll
  for (int i = 0; i < 8; ++i) {
    int l = (tid + i * 256) >> 2;
    float4 v = *(const float4*)(xb + l * 32 + cq * 4);
    v.x = (v.x - m4.x) * r4.x;
    v.y = (v.y - m4.y) * r4.y;
    v.z = (v.z - m4.z) * r4.z;
    v.w = (v.w - m4.w) * r4.w;
    *(float4*)&xs[l * 16 + cq * 4] = v;
  }
  *(float4*)&ks[tid * 4] = *(const float4*)(kf + nb * 1024 + tid * 4);
  __syncthreads();

  int c0 = cq * 4;
  int lg = tid >> 2;
  int l0 = lg * 8;
  float acc[8][4] = {};
  for (int lp = 0; lp < 512; lp += 4) {
    float4 xv[4];
#pragma unroll
    for (int u = 0; u < 4; ++u)
      xv[u] = *(const float4*)&xs[(lp + u) * 16 + c0];
    float kw[12];
    const float* kbp = &ks[l0 - lp + 508];
#pragma unroll
    for (int j = 0; j < 3; ++j)
      *(float4*)&kw[4 * j] = *(const float4*)(kbp + 4 * j);
#pragma unroll
    for (int u = 0; u < 4; ++u) {
      const float* xvp = (const float*)&xv[u];
#pragma unroll
      for (int li = 0; li < 8; ++li) {
        float kv = kw[li - u + 4];
        acc[li][0] = fmaf(kv, xvp[0], acc[li][0]);
        acc[li][1] = fmaf(kv, xvp[1], acc[li][1]);
        acc[li][2] = fmaf(kv, xvp[2], acc[li][2]);
        acc[li][3] = fmaf(kv, xvp[3], acc[li][3]);
      }
    }
  }
  // row = b*8 + l/64, col = (l%64)*32 + ch*16 + c0
  unsigned short* o = (unsigned short*)(xih + (size_t)nb * 4194304 +
                                        (size_t)(b * 8 + (l0 >> 6)) * 2048);
  int colbase = (l0 & 63) * 32 + ch * 16 + c0;
#pragma unroll
  for (int li = 0; li < 8; ++li) {
    union { __hip_bfloat16 h[4]; uint2 u; } P;
    P.h[0] = __float2bfloat16(acc[li][0]);
    P.h[1] = __float2bfloat16(acc[li][1]);
    P.h[2] = __float2bfloat16(acc[li][2]);
    P.h[3] = __float2bfloat16(acc[li][3]);
    *(uint2*)(o + colbase + li * 32) = P.u;
  }
}

// ---------------- fp32 -> bf16 hi/lo split: in [rows,K] -> out [rows,2K] ----------------
__global__ __launch_bounds__(256) void split_kernel(
    const float* __restrict__ in, __hip_bfloat16* __restrict__ out, int ks)
{
  int t = blockIdx.x * 256 + threadIdx.x;
  long long idx = (long long)t * 4;
  int K = 1 << ks;
  long long r = idx >> ks;
  int k = (int)(idx & (K - 1));
  float4 v = *(const float4*)(in + idx);
  float vv[4] = {v.x, v.y, v.z, v.w};
  union { __hip_bfloat16 h[4]; uint2 u; } H, L;
#pragma unroll
  for (int u = 0; u < 4; ++u) {
    H.h[u] = __float2bfloat16(vv[u]);
    L.h[u] = __float2bfloat16(vv[u] - __bfloat162float(H.h[u]));
  }
  unsigned short* ob = (unsigned short*)out + (r << (ks + 1)) + k;
  *(uint2*)ob = H.u;
  *(uint2*)(ob + K) = L.u;
}

// ---------------- split-bf16 MFMA GEMM: C = A*B^T over hi/lo segments ----------------
// 128x128 tile, 256 thr (4 waves 2x2), BK=32, 16x16x32 bf16 MFMA.
// nseg==3: (Ahi*Bhi)+(Ahi*Blo)+(Alo*Bhi); nseg==2: A is hi-only, (A*Bhi)+(A*Blo)
__global__ __launch_bounds__(256) void gemm_mfma(
    const __hip_bfloat16* __restrict__ A, int ldA, long long batchA,
    const __hip_bfloat16* __restrict__ B, int ldB, long long batchB,
    const float* __restrict__ bias, long long batchBias,
    float* __restrict__ Cf, int ldcf, long long batchCf,
    __hip_bfloat16* __restrict__ C2, int nhalf, long long batchC2,
    int M, int N, int K, int nseg, int relu)
{
  __shared__ short sA[128 * 32];
  __shared__ short sB[128 * 32];
  int bz = blockIdx.z;
  const short* Ab = (const short*)A + (long long)bz * batchA;
  const short* Bb = (const short*)B + (long long)bz * batchB;
  int tid = threadIdx.x, wave = tid >> 6, lane = tid & 63;
  int bm = blockIdx.y << 7, bn = blockIdx.x << 7;
  int wrow = (wave >> 1) << 6, wcol = (wave & 1) << 6;

  int sr = lane >> 2;                 // row within a 16-row staging chunk
  int qg = (lane & 3) ^ (sr & 3);     // XOR-swizzled global k-chunk
  int ar0 = wave << 5;                // this wave stages rows [ar0, ar0+32)

  f32x4 acc[4][4];
#pragma unroll
  for (int i = 0; i < 4; ++i)
#pragma unroll
    for (int j = 0; j < 4; ++j)
      acc[i][j] = (f32x4){0.f, 0.f, 0.f, 0.f};

  int frow = lane & 15;
  int fq = lane >> 4;
  int aoffs[4], boffs[4];
#pragma unroll
  for (int i = 0; i < 4; ++i) {
    int ra = wrow + 16 * i + frow;
    aoffs[i] = ra * 32 + ((fq ^ (ra & 3)) << 3);
    int rb = wcol + 16 * i + frow;
    boffs[i] = rb * 32 + ((fq ^ (rb & 3)) << 3);
  }

  for (int seg = 0; seg < nseg; ++seg) {
    int aoff = (seg == 2) ? K : 0;
    int boff = (seg == 1) ? K : 0;
    const short* Aseg = Ab + aoff + (long long)(bm + ar0 + sr) * ldA + qg * 8;
    const short* Bseg = Bb + boff + (long long)(bn + ar0 + sr) * ldB + qg * 8;
    for (int ko = 0; ko < K; ko += 32) {
      gld16(Aseg + ko, &sA[ar0 * 32]);
      gld16(Aseg + ko + 16 * ldA, &sA[(ar0 + 16) * 32]);
      gld16(Bseg + ko, &sB[ar0 * 32]);
      gld16(Bseg + ko + 16 * ldB, &sB[(ar0 + 16) * 32]);
      __syncthreads();
      bf16x8 af[4], bfr[4];
#pragma unroll
      for (int i = 0; i < 4; ++i) af[i] = *(const bf16x8*)&sA[aoffs[i]];
#pragma unroll
      for (int j = 0; j < 4; ++j) bfr[j] = *(const bf16x8*)&sB[boffs[j]];
#pragma unroll
      for (int i = 0; i < 4; ++i)
#pragma unroll
        for (int j = 0; j < 4; ++j)
          acc[i][j] = __builtin_amdgcn_mfma_f32_16x16x32_bf16(
              af[i], bfr[j], acc[i][j], 0, 0, 0);
      __syncthreads();
    }
  }

  // epilogue: C row = bm+wrow+16i+fq*4+r, col = bn+wcol+16j+frow
#pragma unroll
  for (int j = 0; j < 4; ++j) {
    int n = bn + wcol + 16 * j + frow;
    float bv = bias ? bias[(long long)bz * batchBias + n] : 0.f;
#pragma unroll
    for (int i = 0; i < 4; ++i) {
#pragma unroll
      for (int r = 0; r < 4; ++r) {
        int m = bm + wrow + 16 * i + fq * 4 + r;
        float v = acc[i][j][r] + bv;
        if (relu) v = fmaxf(v, 0.f);
        if (Cf) Cf[(long long)bz * batchCf + (long long)m * ldcf + n] = v;
        if (C2) {
          __hip_bfloat16 h = __float2bfloat16(v);
          __hip_bfloat16 l = __float2bfloat16(v - __bfloat162float(h));
          long long base = (long long)bz * batchC2 + (long long)m * (2 * nhalf);
          C2[base + n] = h;
          C2[base + nhalf + n] = l;
        }
      }
    }
  }
}

// ---------------- fp32 NT GEMM (kept for the small recurrence steps) ----------------
__global__ __launch_bounds__(256) void gemm_nt(
    const float* __restrict__ A, int lda, long long batchA,
    const float* __restrict__ B, long long batchB,
    const float* __restrict__ bias, long long batchBias,
    const float* __restrict__ Add, int ldadd, long long batchAdd,
    float* __restrict__ C, int ldc, long long batchC,
    int M, int N, int K, int relu)
{
  int bz = blockIdx.z;
  A += (long long)bz * batchA;
  B += (long long)bz * batchB;
  C += (long long)bz * batchC;

  __shared__ float As[16][68];
  __shared__ float Bs[16][68];

  int tid = threadIdx.x;
  int lr = tid >> 2;
  int lk = (tid & 3) << 2;
  int tm = ((tid >> 4) & 15) << 2;
  int tn = (tid & 15) << 2;
  int bm = blockIdx.y << 6;
  int bn = blockIdx.x << 6;

  const float* Ap = A + (long long)(bm + lr) * lda + lk;
  const float* Bp = B + (long long)(bn + lr) * K + lk;

  float acc[4][4] = {};

  for (int kb = 0; kb < K; kb += 16) {
    float4 av = *(const float4*)(Ap + kb);
    float4 bv = *(const float4*)(Bp + kb);
    As[lk + 0][lr] = av.x; As[lk + 1][lr] = av.y;
    As[lk + 2][lr] = av.z; As[lk + 3][lr] = av.w;
    Bs[lk + 0][lr] = bv.x; Bs[lk + 1][lr] = bv.y;
    Bs[lk + 2][lr] = bv.z; Bs[lk + 3][lr] = bv.w;
    __syncthreads();
#pragma unroll
    for (int k = 0; k < 16; ++k) {
      float4 a4 = *(const float4*)&As[k][tm];
      float4 b4 = *(const float4*)&Bs[k][tn];
      const float* a = (const float*)&a4;
      const float* bq = (const float*)&b4;
#pragma unroll
      for (int i = 0; i < 4; ++i)
#pragma unroll
        for (int j = 0; j < 4; ++j)
          acc[i][j] = fmaf(a[i], bq[j], acc[i][j]);
    }
    __syncthreads();
  }

  float4 bb4 = make_float4(0.f, 0.f, 0.f, 0.f);
  if (bias) bb4 = *(const float4*)(bias + (long long)bz * batchBias + bn + tn);
  const float* addp = Add ? Add + (long long)bz * batchAdd : nullptr;
#pragma unroll
  for (int i = 0; i < 4; ++i) {
    int m = bm + tm + i;
    float4 o = make_float4(acc[i][0] + bb4.x, acc[i][1] + bb4.y,
                           acc[i][2] + bb4.z, acc[i][3] + bb4.w);
    if (addp) {
      float4 ad = *(const float4*)(addp + (long long)m * ldadd + bn + tn);
      o.x += ad.x; o.y += ad.y; o.z += ad.z; o.w += ad.w;
    }
    if (relu) {
      o.x = fmaxf(o.x, 0.f); o.y = fmaxf(o.y, 0.f);
      o.z = fmaxf(o.z, 0.f); o.w = fmaxf(o.w, 0.f);
    }
    *(float4*)(C + (long long)m * ldc + bn + tn) = o;
  }
}

// ---------------- LayerNorm over 512, writes bf16 hi/lo [row, 1024] ----------------
__global__ __launch_bounds__(256) void ln_kernel(
    const float* __restrict__ p, const float* __restrict__ g,
    const float* __restrict__ bb, __hip_bfloat16* __restrict__ p2)
{
  int row = blockIdx.x;              // NB*B*4 = 4096
  int nb = row >> 10;
  const float* pr = p + (size_t)row * 512;
  int tid = threadIdx.x;
  float v0 = pr[tid], v1 = pr[tid + 256];
  float s = v0 + v1, s2 = v0 * v0 + v1 * v1;
#pragma unroll
  for (int o = 32; o > 0; o >>= 1) {
    s += __shfl_down(s, o);
    s2 += __shfl_down(s2, o);
  }
  __shared__ float rs[4];
  __shared__ float rs2[4];
  int w = tid >> 6;
  if ((tid & 63) == 0) { rs[w] = s; rs2[w] = s2; }
  __syncthreads();
  s = rs[0] + rs[1] + rs[2] + rs[3];
  s2 = rs2[0] + rs2[1] + rs2[2] + rs2[3];
  float mval = s * (1.f / 512.f);
  float var = s2 * (1.f / 512.f) - mval * mval;
  float r = 1.f / sqrtf(var + EPSF);
  const float* gn = g + nb * 512;
  const float* bn = bb + nb * 512;
  float y0 = (v0 - mval) * r * gn[tid] + bn[tid];
  float y1 = (v1 - mval) * r * gn[tid + 256] + bn[tid + 256];
  __hip_bfloat16* o2 = p2 + (size_t)nb * 1048576 + (size_t)(row & 1023) * 1024;
  __hip_bfloat16 h0 = __float2bfloat16(y0);
  __hip_bfloat16 h1 = __float2bfloat16(y1);
  o2[tid] = h0;
  o2[tid + 256] = h1;
  o2[512 + tid] = __float2bfloat16(y0 - __bfloat162float(h0));
  o2[768 + tid] = __float2bfloat16(y1 - __bfloat162float(h1));
}

// ---------------- final: out = (sum_nb deco) * std + mean ----------------
__global__ __launch_bounds__(256) void final_kernel(
    const float* __restrict__ deco, const float* __restrict__ meanp,
    const float* __restrict__ stdp, float* __restrict__ out)
{
  int t = blockIdx.x * 256 + threadIdx.x;
  int b = t >> 11;
  int r = t & 2047;
  int s = r >> 9;
  int p = (r >> 3) & 63;
  int cq = r & 7;
  size_t base = ((size_t)(b * 4 + s)) * 2048 + p * 32 + cq * 4;
  const size_t nbs = 1024ull * 2048ull;
  float4 a0 = *(const float4*)(deco + base);
  float4 a1 = *(const float4*)(deco + nbs + base);
  float4 a2 = *(const float4*)(deco + 2 * nbs + base);
  float4 a3 = *(const float4*)(deco + 3 * nbs + base);
  float4 m4 = *(const float4*)(meanp + b * 32 + cq * 4);
  float4 s4 = *(const float4*)(stdp + b * 32 + cq * 4);
  float4 o;
  o.x = (a0.x + a1.x + a2.x + a3.x) * s4.x + m4.x;
  o.y = (a0.y + a1.y + a2.y + a3.y) * s4.y + m4.y;
  o.z = (a0.z + a1.z + a2.z + a3.z) * s4.z + m4.z;
  o.w = (a0.w + a1.w + a2.w + a3.w) * s4.w + m4.w;
  *(float4*)(out + (size_t)t * 4) = o;
}

extern "C" void kernel_launch(void* const* d_in, const int* in_sizes, int n_in,
                              void* d_out, int out_size, void* d_ws, size_t ws_size,
                              hipStream_t stream) {
  const float* x_enc  = (const float*)d_in[0];
  const float* mask_w = (const float*)d_in[4];
  const float* enc_w1 = (const float*)d_in[5];
  const float* enc_b1 = (const float*)d_in[6];
  const float* enc_w2 = (const float*)d_in[7];
  const float* enc_b2 = (const float*)d_in[8];
  const float* wxh    = (const float*)d_in[9];
  const float* whh    = (const float*)d_in[10];
  const float* ln_g   = (const float*)d_in[11];
  const float* ln_b   = (const float*)d_in[12];
  const float* dec_w1 = (const float*)d_in[13];
  const float* dec_b1 = (const float*)d_in[14];
  const float* dec_w2 = (const float*)d_in[15];
  const float* dec_b2 = (const float*)d_in[16];
  float* out = (float*)d_out;

  // ---- workspace layout (bytes); peak ~96 MiB (< 124 MiB proven in R1) ----
  char* W = (char*)d_ws;
  float* MEAN = (float*)(W + 0);
  float* STD  = (float*)(W + 32768);
  float* RSTD = (float*)(W + 65536);
  float* KF   = (float*)(W + 98304);
  char* B0 = W + 131072;
  __hip_bfloat16* XIH   = (__hip_bfloat16*)(B0);               // 32MB [4][2048][2048] hi
  __hip_bfloat16* WW    = (__hip_bfloat16*)(B0 + 33554432);    // 32MB enc_w1_2 / later dec_w2_2
  __hip_bfloat16* ENCB2 = (__hip_bfloat16*)(B0 + 67108864);    // 32MB [4][2048][2048] hi|lo
  // after enc1 (XIH region reused):
  __hip_bfloat16* EW2    = (__hip_bfloat16*)(B0);              // 8MB
  __hip_bfloat16* WXH2   = (__hip_bfloat16*)(B0 + 8388608);    // 4MB
  __hip_bfloat16* DW1    = (__hip_bfloat16*)(B0 + 12582912);   // 8MB
  __hip_bfloat16* PREDS2 = (__hip_bfloat16*)(B0 + 20971520);   // 8MB
  __hip_bfloat16* ENC22  = WW;                                 // 16MB (WW reuse)
  __hip_bfloat16* DW2    = WW;                                 // 32MB (after xp)
  float* XP    = (float*)(B0 + 67108864);                      // 16MB (ENCB2 reuse)
  float* H0    = (float*)(B0 + 67108864 + 16777216);           // 2MB
  float* H1    = (float*)(B0 + 67108864 + 18874368);           // 2MB
  float* PREDS = (float*)(B0 + 67108864 + 20971520);           // 8MB
  __hip_bfloat16* DBUF2 = (__hip_bfloat16*)(B0 + 67108864);    // 16MB (XP reuse after rec)
  float* DECO  = (float*)(B0);                                 // 32MB (XIH region reuse)

  stats_kernel<<<256, 256, 0, stream>>>(x_enc, MEAN, STD, RSTD);
  kfilt_kernel<<<8, 256, 0, stream>>>(mask_w, KF);
  conv_kernel<<<dim3(256, 4, 2), 256, 0, stream>>>(x_enc, MEAN, RSTD, KF, XIH);

  // weight splits (fp32 -> [rows,2K] bf16 hi|lo)
  split_kernel<<<8192, 256, 0, stream>>>(enc_w1, WW, 11);
  // enc1: M=2048 N=1024 K=2048, A hi-only (nseg=2), relu, split-out
  gemm_mfma<<<dim3(8, 16, 4), 256, 0, stream>>>(
      XIH, 2048, 4194304LL, WW, 4096, 4194304LL, enc_b1, 1024LL,
      nullptr, 0, 0LL, ENCB2, 1024, 4194304LL, 2048, 1024, 2048, 2, 1);

  split_kernel<<<2048, 256, 0, stream>>>(enc_w2, EW2, 10);
  split_kernel<<<1024, 256, 0, stream>>>(wxh, WXH2, 9);
  split_kernel<<<2048, 256, 0, stream>>>(dec_w1, DW1, 9);

  // enc2: M=2048 N=512 K=1024, nseg=3, split-out
  gemm_mfma<<<dim3(4, 16, 4), 256, 0, stream>>>(
      ENCB2, 2048, 4194304LL, EW2, 2048, 1048576LL, enc_b2, 512LL,
      nullptr, 0, 0LL, ENC22, 512, 2097152LL, 2048, 512, 1024, 3, 0);
  // xp = enc2 @ wxh^T: fp32 out
  gemm_mfma<<<dim3(4, 16, 4), 256, 0, stream>>>(
      ENC22, 1024, 2097152LL, WXH2, 1024, 524288LL, nullptr, 0LL,
      XP, 512, 1048576LL, nullptr, 0, 0LL, 2048, 512, 512, 3, 0);

  split_kernel<<<8192, 256, 0, stream>>>(dec_w2, DW2, 10);  // after xp: ENC22 dead

  // recurrence (fp32): h_0 = xp_0; h_f = h_{f-1} @ whh^T + xp_f
  const float* hin = XP; int lda_h = 4096; long long batchA_h = 1048576LL;
  float* hbuf[2] = {H0, H1};
  for (int f = 1; f < 8; ++f) {
    float* hout = hbuf[(f - 1) & 1];
    gemm_nt<<<dim3(8, 4, 4), 256, 0, stream>>>(
        hin, lda_h, batchA_h, whh, 262144LL, nullptr, 0LL,
        XP + f * 512, 4096, 1048576LL, hout, 512, 131072LL, 256, 512, 512, 0);
    hin = hout; lda_h = 512; batchA_h = 131072LL;
  }
  for (int s = 0; s < 4; ++s) {
    gemm_nt<<<dim3(8, 4, 4), 256, 0, stream>>>(
        hin, lda_h, batchA_h, whh, 262144LL, nullptr, 0LL,
        nullptr, 0, 0LL, PREDS + s * 512, 2048, 524288LL, 256, 512, 512, 0);
    hin = PREDS + s * 512; lda_h = 2048; batchA_h = 524288LL;
  }

  ln_kernel<<<4096, 256, 0, stream>>>(PREDS, ln_g, ln_b, PREDS2);

  // dec1: M=1024 N=1024 K=512, nseg=3, relu, split-out
  gemm_mfma<<<dim3(8, 8, 4), 256, 0, stream>>>(
      PREDS2, 1024, 1048576LL, DW1, 1024, 1048576LL, dec_b1, 1024LL,
      nullptr, 0, 0LL, DBUF2, 1024, 2097152LL, 1024, 1024, 512, 3, 1);
  // dec2: M=1024 N=2048 K=1024, nseg=3, fp32 out
  gemm_mfma<<<dim3(16, 8, 4), 256, 0, stream>>>(
      DBUF2, 2048, 2097152LL, DW2, 2048, 4194304LL, dec_b2, 2048LL,
      DECO, 2048, 2097152LL, nullptr, 0, 0LL, 1024, 2048, 1024, 3, 0);

  final_kernel<<<2048, 256, 0, stream>>>(DECO, MEAN, STD, out);
}